// Round 10
// baseline (880.369 us; speedup 1.0000x reference)
//
#include <hip/hip_runtime.h>
#include <math.h>

#define BB 128
#define TT 1024
#define DD 128
#define HH 64
#define G3 192   // 3*H
#define KK 32
#define CH 32

// ---------------------------------------------------------------------------
// R10: fold xproj into the GRU blocks as a private pre-phase (single dispatch).
// R9 (WIN, 746us = 166 xproj + 580 gruvit) proved: removing viterbi from the
// barrier race cut the recurrence 732->580us; GRU->VIT flag protocol proven.
// The standalone xproj runs at 2.4 TF (1.5% of peak) -- latency-bound, not
// compute-bound. Per batch it's only ~6144 FMAs/lane for 256 threads (~10us).
// So: each GRU block computes ITS OWN xp[b] first (phase 1), then runs the
// R9 recurrence (phase 2) reading it back through its own L1/L2. No flags,
// no fence, no new cross-block edges: dependency graph == R9 (one-way
// GRU->VIT pot flags), same deadlock-safety evidence.
//   Phase 1 (GRU blocks): Wk staged once -> Ws[128][196] LDS (100KB); 16x
//     64-row tiles, R0's exact 4x4-acc k-ascending arithmetic (strides don't
//     affect values) -> bitwise-identical xp.
//   Phase 2: R9 GRU body verbatim (3 gate waves + pot/staging wave, 1
//     barrier/step, pot chunk flags at (i&31)==4).
//   VIT blocks: R9 verbatim (flag-spin stager + chunked viterbi + backtrack).
// ---------------------------------------------------------------------------
#define BCAST(v, l) __int_as_float(__builtin_amdgcn_readlane(__float_as_int(v), (l)))

__device__ int g_pflags[BB * 32];   // zero-initialized at module load

__global__ __launch_bounds__(256, 1)
void gruvit_kernel(const float* __restrict__ X,
                   const float* __restrict__ Wk,
                   const float* __restrict__ xp,
                   const float* __restrict__ Wr,
                   const float* __restrict__ gbias,
                   const int* __restrict__ mask,
                   const float* __restrict__ Dk,
                   const float* __restrict__ db,
                   const float* __restrict__ chain,
                   const float* __restrict__ lb,
                   const float* __restrict__ rb,
                   float* __restrict__ out_pot,
                   float* __restrict__ out_dec,
                   float* __restrict__ out_slen,
                   float* __restrict__ out_chn) {
    __shared__ __align__(16) unsigned char smem[134144];
    const int tid = threadIdx.x;
    const int w = tid >> 6;
    const int l = tid & 63;

    if (blockIdx.x < BB) {
        // =================== GRU block ======================================
        const int b = blockIdx.x;
        const int bTT = b * TT;

        // ---- phase 1: xproj for this batch (R0 tiling, bitwise-identical) --
        {
            float* Xs = (float*)smem;                    // [64][132]  33792 B
            float* Ws = (float*)(smem + 33792);          // [128][196] 100352 B
            // stage Wk -> Ws (24576 floats = 6144 float4 over 256 threads)
#pragma unroll
            for (int it = 0; it < 24; ++it) {
                int idx = it * 256 + tid;
                int kr = idx / 48, cc = (idx % 48) * 4;
                float4 v = *(const float4*)&Wk[(size_t)kr * G3 + cc];
                *(float4*)&Ws[kr * 196 + cc] = v;
            }
            const int tr = tid >> 4, tc = tid & 15;
            const int r0 = tr * 4, c0 = tc * 4;
            float* xpw = (float*)xp + (size_t)bTT * G3;
            for (int rt = 0; rt < 16; ++rt) {
                const int row0 = rt * 64;
#pragma unroll
                for (int it = 0; it < 8; ++it) {
                    int idx = it * 256 + tid;
                    int r = idx >> 5, c4 = (idx & 31) << 2;
                    float4 v = *(const float4*)&X[((size_t)(bTT + row0 + r)) * DD + c4];
                    *(float4*)&Xs[r * 132 + c4] = v;
                }
                __syncthreads();               // Xs (and 1st iter Ws) ready
                for (int cg = 0; cg < 3; ++cg) {
                    float acc[4][4];
#pragma unroll
                    for (int r = 0; r < 4; ++r)
#pragma unroll
                        for (int c = 0; c < 4; ++c) acc[r][c] = 0.f;
#pragma unroll 4
                    for (int k2 = 0; k2 < DD; k2 += 4) {
                        float a[4][4];
#pragma unroll
                        for (int r = 0; r < 4; ++r) {
                            float4 t = *(const float4*)&Xs[(r0 + r) * 132 + k2];
                            a[r][0] = t.x; a[r][1] = t.y; a[r][2] = t.z; a[r][3] = t.w;
                        }
#pragma unroll
                        for (int kk = 0; kk < 4; ++kk) {
                            float4 bv = *(const float4*)&Ws[(k2 + kk) * 196 + cg * 64 + c0];
#pragma unroll
                            for (int r = 0; r < 4; ++r) {
                                acc[r][0] += a[r][kk] * bv.x;
                                acc[r][1] += a[r][kk] * bv.y;
                                acc[r][2] += a[r][kk] * bv.z;
                                acc[r][3] += a[r][kk] * bv.w;
                            }
                        }
                    }
                    float4 bias = *(const float4*)&gbias[cg * 64 + c0];
#pragma unroll
                    for (int r = 0; r < 4; ++r) {
                        float4 o;
                        o.x = acc[r][0] + bias.x; o.y = acc[r][1] + bias.y;
                        o.z = acc[r][2] + bias.z; o.w = acc[r][3] + bias.w;
                        *(float4*)&xpw[((size_t)(row0 + r0 + r)) * G3 + cg * 64 + c0] = o;
                    }
                }
                __syncthreads();               // Xs reusable next tile
            }
        }
        // (L1 is per-CU and this block reads back only its own writes ->
        //  no fence needed between phases; trailing barrier above suffices.)

        // ---- phase 2: R9 recurrence verbatim -------------------------------
        float (*gbuf)[4 * HH]     = (float (*)[4 * HH])(smem);           // 2048
        float (*hbuf)[HH]         = (float (*)[HH])(smem + 2048);        // 1024
        float (*potring)[KK]      = (float (*)[KK])(smem + 3072);        // 8192
        float (*xpstage)[CH * G3] = (float (*)[CH * G3])(smem + 11264);  // 49152
        int (*maskst)[CH]         = (int (*)[CH])(smem + 60416);         // 256

        if (w < 3) {
            // ---- GRU gate waves (R0/R9 verbatim) ----
            const int j = l;
            float wg[HH];
#pragma unroll
            for (int i2 = 0; i2 < HH; ++i2) wg[i2] = Wr[i2 * G3 + w * HH + j];
#pragma unroll
            for (int i2 = 0; i2 < HH; ++i2) asm volatile("" : "+v"(wg[i2]));
            const float bw = gbias[G3 + w * HH + j];
            __builtin_amdgcn_s_setprio(1);
            float h = 0.f;
            __syncthreads();                                  // pre-loop barrier
            float xv0 = xpstage[0][tid];                      // xv(0)
            int m0 = maskst[0][0];                            // m(0), broadcast
            for (int i = 0; i < TT + 2; ++i) {
                if (i < TT) {
                    float a0 = bw, a1 = 0.f, a2 = 0.f, a3 = 0.f;
#pragma unroll
                    for (int c = 0; c < HH; c += 4) {
                        a0 += BCAST(h, c + 0) * wg[c + 0];
                        a1 += BCAST(h, c + 1) * wg[c + 1];
                        a2 += BCAST(h, c + 2) * wg[c + 2];
                        a3 += BCAST(h, c + 3) * wg[c + 3];
                    }
                    float a = (a0 + a1) + (a2 + a3);
                    float g = (w == 2) ? a : 1.f / (1.f + __expf(-(xv0 + a)));
                    gbuf[i & 1][w * HH + j] = g;
                    if (w == 2) gbuf[i & 1][3 * HH + j] = xv0;
                }
                __syncthreads();
                if (i < TT) {
                    float z  = gbuf[i & 1][j];
                    float r  = gbuf[i & 1][HH + j];
                    float rh = gbuf[i & 1][2 * HH + j];
                    float xh = gbuf[i & 1][3 * HH + j];
                    float y = xh + r * rh;
                    float hh = 1.f - 2.f / (1.f + __expf(2.f * y));   // tanh
                    float hn = z * h + (1.f - z) * hh;
                    hn = (m0 != 0) ? hn : h;
                    h = hn;
                    if (w == 0) hbuf[i & 3][j] = hn;
                    if (i < TT - 1) {                        // prefetch step i+1
                        const int t1 = i + 1;
                        xv0 = xpstage[(t1 >> 5) & 1][(t1 & 31) * G3 + tid];
                        m0  = maskst[(t1 >> 5) & 1][t1 & 31];
                    }
                }
            }
        } else {
            // ---- pot matvec + chunk staging wave (R9 verbatim) ----
            const int k = l & 31;
            int sl = 0;
#pragma unroll
            for (int q = 0; q < 16; ++q) sl += mask[bTT + q * 64 + l];
#pragma unroll
            for (int d = 32; d >= 1; d >>= 1) sl += __shfl_xor(sl, d, 64);
            if (l == 0) out_slen[b] = (float)sl;
            float dk[HH];
#pragma unroll
            for (int i2 = 0; i2 < HH; ++i2) dk[i2] = Dk[i2 * KK + k];
#pragma unroll
            for (int i2 = 0; i2 < HH; ++i2) asm volatile("" : "+v"(dk[i2]));
            const float dbk = db[k], lbk = lb[k], rbk = rb[k];
            const float* xpg = xp + (size_t)bTT * G3;
            float* potg = out_pot + (size_t)bTT * KK;
            // stage chunk 0
#pragma unroll
            for (int q = 0; q < 24; ++q) {
                float4 v = *(const float4*)&xpg[q * 256 + l * 4];
                *(float4*)&xpstage[0][q * 256 + l * 4] = v;
            }
            if (l < CH) maskst[0][l] = mask[bTT + l];
            __syncthreads();                                  // pre-loop barrier
            for (int i = 0; i < TT + 2; ++i) {
                if ((i & 31) == 0) {
                    const int cn = (i >> 5) + 1;              // stage chunk cn
                    if (cn < 32) {
                        const float* src = xpg + (size_t)cn * CH * G3;
                        float* dst = &xpstage[cn & 1][0];
#pragma unroll
                        for (int q = 0; q < 24; ++q) {
                            float4 v = *(const float4*)&src[q * 256 + l * 4];
                            *(float4*)&dst[q * 256 + l * 4] = v;
                        }
                        if (l < CH) maskst[cn & 1][l] = mask[bTT + cn * CH + l];
                    }
                    const int cf = (i >> 5) - 2;              // flush pot chunk cf
                    if (cf >= 0) {
                        const float* srcl = &potring[(cf & 1) * 32][0];
                        float* dstg = potg + (size_t)cf * CH * KK;
#pragma unroll
                        for (int q = 0; q < 4; ++q) {
                            float4 v = *(const float4*)&srcl[q * 256 + l * 4];
                            *(float4*)&dstg[q * 256 + l * 4] = v;
                        }
                    }
                }
                // publish chunk flushed 4 steps ago (stores long complete)
                if ((i & 31) == 4 && l == 0) {
                    const int cp = (i >> 5) - 2;
                    if (cp >= 0) {
                        __threadfence();
                        atomicExch(&g_pflags[b * 32 + cp], 1);
                    }
                }
                const int t = i - 2;
                if (t >= 0 && t < TT) {
                    const float4* hv4 = (const float4*)&hbuf[t & 3][0];
                    float p0 = dbk, p1 = 0.f, p2 = 0.f, p3 = 0.f;
#pragma unroll
                    for (int c = 0; c < 16; ++c) {
                        float4 hv = hv4[c];
                        p0 += hv.x * dk[4 * c + 0];
                        p1 += hv.y * dk[4 * c + 1];
                        p2 += hv.z * dk[4 * c + 2];
                        p3 += hv.w * dk[4 * c + 3];
                    }
                    float pot = (p0 + p1) + (p2 + p3);
                    if (t == 0) pot += lbk;
                    if (t == sl - 1) pot += rbk;
                    if (l < 32) potring[t & 63][k] = pot;
                }
                __syncthreads();
            }
            // flush last pot chunk (31), publish 30 and 31
            {
                const float* srcl = &potring[(31 & 1) * 32][0];
                float* dstg = potg + (size_t)31 * CH * KK;
#pragma unroll
                for (int q = 0; q < 4; ++q) {
                    float4 v = *(const float4*)&srcl[q * 256 + l * 4];
                    *(float4*)&dstg[q * 256 + l * 4] = v;
                }
                if (l == 0) {
                    __threadfence();
                    atomicExch(&g_pflags[b * 32 + 30], 1);
                    atomicExch(&g_pflags[b * 32 + 31], 1);
                }
            }
        }
        return;
    }

    // =================== VIT block (R9 verbatim) ============================
    const int b = blockIdx.x - BB;
    const int bTT = b * TT;
    const float* potg = out_pot + (size_t)bTT * KK;
    const int k = l & 31;
    const int hf = l >> 5;
    const int addrx = (l ^ 32) * 4;

    unsigned char* bp    = smem;                                   // 32736
    unsigned char* table = smem + 32736;                           // 32768
    float (*potbuf)[CH][KK] = (float (*)[CH][KK])(smem + 65504);   // 8192
    int* ent        = (int*)(smem + 73696);                        // 128
    int* last_tag_s = (int*)(smem + 73824);                        // 4

    float ccol[16];
    int addr[16];
    if (w == 1) {
#pragma unroll
        for (int m = 0; m < 16; ++m) {
            ccol[m] = chain[(hf * 16 + m) * KK + k];
            addr[m] = (hf * 16 + m) * 4;
        }
#pragma unroll
        for (int m = 0; m < 16; ++m) asm volatile("" : "+v"(ccol[m]));
    }
    // stage chunk 0
    if (w == 0) {
        if (l == 0) {
            while (atomicAdd(&g_pflags[b * 32 + 0], 0) == 0) __builtin_amdgcn_s_sleep(8);
        }
        __threadfence();                                  // acquire
#pragma unroll
        for (int q = 0; q < 4; ++q) {
            float4 v = *(const float4*)&potg[(size_t)(q * 64 + l) * 4];
            ((float4*)&potbuf[0][0][0])[q * 64 + l] = v;
        }
    }
    __syncthreads();                                      // B0: chunk 0 ready
    float s = 0.f;
    for (int c = 0; c < 32; ++c) {
        if (w == 0 && c + 1 < 32) {                       // stage chunk c+1
            if (l == 0) {
                while (atomicAdd(&g_pflags[b * 32 + c + 1], 0) == 0)
                    __builtin_amdgcn_s_sleep(8);
            }
            __threadfence();
            const float* src = potg + (size_t)(c + 1) * CH * KK;
#pragma unroll
            for (int q = 0; q < 4; ++q) {
                float4 v = *(const float4*)&src[(size_t)(q * 64 + l) * 4];
                ((float4*)&potbuf[(c + 1) & 1][0][0])[q * 64 + l] = v;
            }
        }
        if (w == 1) {                                     // viterbi chunk c
            for (int ll = 0; ll < 32; ++ll) {
                const int t = c * 32 + ll;
                float pot = potbuf[c & 1][ll][k];
                if (t == 0) {
                    s = pot;
                } else {
                    const int si = __float_as_int(s);
                    float cc[16];
#pragma unroll
                    for (int m = 0; m < 16; ++m)
                        cc[m] = __int_as_float(__builtin_amdgcn_ds_bpermute(addr[m], si)) + ccol[m];
                    float v1[8]; int i1[8];
#pragma unroll
                    for (int p = 0; p < 8; ++p) {
                        bool tk = cc[2 * p + 1] > cc[2 * p];
                        v1[p] = tk ? cc[2 * p + 1] : cc[2 * p];
                        i1[p] = hf * 16 + (tk ? 2 * p + 1 : 2 * p);
                    }
                    float v2[4]; int i2[4];
#pragma unroll
                    for (int p = 0; p < 4; ++p) {
                        bool tk = v1[2 * p + 1] > v1[2 * p];
                        v2[p] = tk ? v1[2 * p + 1] : v1[2 * p];
                        i2[p] = tk ? i1[2 * p + 1] : i1[2 * p];
                    }
                    float v3[2]; int i3[2];
#pragma unroll
                    for (int p = 0; p < 2; ++p) {
                        bool tk = v2[2 * p + 1] > v2[2 * p];
                        v3[p] = tk ? v2[2 * p + 1] : v2[2 * p];
                        i3[p] = tk ? i2[2 * p + 1] : i2[2 * p];
                    }
                    bool tk = v3[1] > v3[0];
                    float bv = tk ? v3[1] : v3[0];
                    int bi = tk ? i3[1] : i3[0];
                    float ov = __int_as_float(__builtin_amdgcn_ds_bpermute(addrx, __float_as_int(bv)));
                    int   oi = __builtin_amdgcn_ds_bpermute(addrx, bi);
                    bool take = (ov > bv) || (ov == bv && oi < bi);
                    if (take) { bv = ov; bi = oi; }
                    if (l < 32) bp[(t - 1) * KK + k] = (unsigned char)bi;
                    s = bv + pot;
                }
            }
        }
        __syncthreads();                                  // chunk boundary
    }
    if (w == 1) {                                         // last tag
        float bv = s; int bi = k;
#pragma unroll
        for (int d = 16; d >= 1; d >>= 1) {
            float ov = __shfl_xor(bv, d, 64);
            int   oi = __shfl_xor(bi, d, 64);
            bool take = (ov > bv) || (ov == bv && oi < bi);
            if (take) { bv = ov; bi = oi; }
        }
        if (l == 0) *last_tag_s = bi;
    }
    __syncthreads();
    // ---- Phase A: chunk-parallel backtrack (8 groups over 32 chunks) ----
    {
        const int kk2 = tid & 31;
        const int grp = tid >> 5;                         // 0..7
        for (int c = grp; c < 32; c += 8) {
            int tag = kk2;
            for (int ll = 31; ll >= 0; --ll) {
                const int t = c * 32 + ll;
                if (t < TT - 1) tag = bp[t * KK + tag];
                table[(c * 32 + ll) * KK + kk2] = (unsigned char)tag;
            }
        }
    }
    __syncthreads();
    if (tid == 0) {                                       // Phase B: stitch
        int e = *last_tag_s;
        ent[31] = e;
        for (int c = 30; c >= 0; --c) { e = table[(c + 1) * 32 * KK + e]; ent[c] = e; }
    }
    __syncthreads();
    for (int t = tid; t < TT; t += 256) {                 // Phase C: emit
        const int c = t >> 5, ll = t & 31;
        out_dec[(size_t)bTT + t] = (float)table[(c * 32 + ll) * KK + ent[c]];
    }
    if (blockIdx.x == BB) {
        for (int i2 = tid; i2 < KK * KK; i2 += 256) out_chn[i2] = chain[i2];
    }
    // re-zero this batch's flags for the next launch/replay
    for (int i2 = tid; i2 < 32; i2 += 256) atomicExch(&g_pflags[b * 32 + i2], 0);
}

// ---------------------------------------------------------------------------
extern "C" void kernel_launch(void* const* d_in, const int* in_sizes, int n_in,
                              void* d_out, int out_size, void* d_ws, size_t ws_size,
                              hipStream_t stream) {
    const float* X     = (const float*)d_in[0];
    const int*   mask  = (const int*)d_in[1];
    const float* Wk    = (const float*)d_in[2];   // [128,192]
    const float* Wr    = (const float*)d_in[3];   // [64,192]
    const float* gb    = (const float*)d_in[4];   // [2,192]
    const float* Dk    = (const float*)d_in[5];   // [64,32]
    const float* db    = (const float*)d_in[6];   // [32]
    const float* chain = (const float*)d_in[7];   // [32,32]
    const float* lb    = (const float*)d_in[8];
    const float* rb    = (const float*)d_in[9];

    float* out = (float*)d_out;
    float* out_dec  = out;                                   // [B,T]
    float* out_pot  = out + (size_t)BB * TT;                 // [B,T,K]
    float* out_slen = out + (size_t)BB * TT + (size_t)BB * TT * KK;        // [B]
    float* out_chn  = out_slen + BB;                         // [K,K]

    float* xp = (float*)d_ws;                                // [B*T,192]

    gruvit_kernel<<<dim3(2 * BB), dim3(256), 0, stream>>>(X, Wk, xp, Wr, gb, mask,
                                                          Dk, db, chain, lb, rb,
                                                          out_pot, out_dec,
                                                          out_slen, out_chn);
}

// Round 11
// 742.917 us; speedup vs baseline: 1.1850x; 1.1850x over previous
//
#include <hip/hip_runtime.h>
#include <math.h>

#define BB 128
#define TT 1024
#define DD 128
#define HH 64
#define G3 192   // 3*H
#define KK 32
#define CH 32

// ---------------------------------------------------------------------------
// R11: evict the pot/staging wave from the GRU barrier race (the R9 lever,
// applied again). R10's in-block xproj regressed (+260us serial pre-phase) ->
// reverted to R9's two-dispatch structure.
//   K1 xproj: R0 verbatim (166us proven).
//   K2 grid 256 x 256thr:
//     blocks 0..127 GRU: 4 waves, 1 barrier/step, NO LDS except gbuf(2KB).
//       w0-2: gate dots (R9-verbatim readlane/4-acc math), xv loaded DIRECTLY
//             from global with 2-step prefetch (xp is L2/L3-hot; 1 b32/step).
//       w3:   barrier companion; recomputes hn from gbuf (every wave already
//             does), stores h(t) into xp[t][0:64] (slot consumed 2 steps
//             earlier; barrier-ordered), publishes h-chunk flags (proven
//             fence+atomic protocol, same-wave vmcnt).
//     blocks 128..255 VIT: R9 structure; stager wave now loads h chunks and
//       COMPUTES pot (bitwise-identical float4-broadcast p0..p3 order, same
//       lb/rb/db adds) into potbuf + out_pot; viterbi/backtrack verbatim.
// All numeric paths mirror proven kernels -> absmax unchanged.
// ---------------------------------------------------------------------------
#define BCAST(v, l) __int_as_float(__builtin_amdgcn_readlane(__float_as_int(v), (l)))

__device__ int g_pflags[BB * 32];   // zero-initialized at module load

// ============================ K1: xproj (R0 verbatim) =======================
__global__ __launch_bounds__(256, 2) void xproj_kernel(const float* __restrict__ X,
                                                       const float* __restrict__ Wk,
                                                       const float* __restrict__ gbias,
                                                       float* __restrict__ xp) {
    __shared__ float Xs[64 * 132];
    __shared__ float Ws[128 * 68];
    const int tid = threadIdx.x;
    const int row0 = blockIdx.x * 64;
    const int cg = blockIdx.y;
#pragma unroll
    for (int it = 0; it < 8; ++it) {
        int idx = it * 1024 + tid * 4;
        int r = idx >> 7, c = idx & 127;
        float4 v = *(const float4*)&X[((size_t)(row0 + r)) * DD + c];
        *(float4*)&Xs[r * 132 + c] = v;
    }
#pragma unroll
    for (int it = 0; it < 8; ++it) {
        int idx = it * 1024 + tid * 4;
        int k = idx >> 6, c = idx & 63;
        float4 v = *(const float4*)&Wk[(size_t)k * G3 + cg * 64 + c];
        *(float4*)&Ws[k * 68 + c] = v;
    }
    __syncthreads();
    const int tr = tid >> 4, tc = tid & 15;
    const int r0 = tr * 4, c0 = tc * 4;
    float acc[4][4];
#pragma unroll
    for (int r = 0; r < 4; ++r)
#pragma unroll
        for (int c = 0; c < 4; ++c) acc[r][c] = 0.f;
#pragma unroll 4
    for (int k = 0; k < DD; k += 4) {
        float a[4][4];
#pragma unroll
        for (int r = 0; r < 4; ++r) {
            float4 t = *(const float4*)&Xs[(r0 + r) * 132 + k];
            a[r][0] = t.x; a[r][1] = t.y; a[r][2] = t.z; a[r][3] = t.w;
        }
#pragma unroll
        for (int kk = 0; kk < 4; ++kk) {
            float4 b = *(const float4*)&Ws[(k + kk) * 68 + c0];
#pragma unroll
            for (int r = 0; r < 4; ++r) {
                acc[r][0] += a[r][kk] * b.x;
                acc[r][1] += a[r][kk] * b.y;
                acc[r][2] += a[r][kk] * b.z;
                acc[r][3] += a[r][kk] * b.w;
            }
        }
    }
    float4 bias = *(const float4*)&gbias[cg * 64 + c0];
#pragma unroll
    for (int r = 0; r < 4; ++r) {
        float4 o;
        o.x = acc[r][0] + bias.x; o.y = acc[r][1] + bias.y;
        o.z = acc[r][2] + bias.z; o.w = acc[r][3] + bias.w;
        *(float4*)&xp[((size_t)(row0 + r0 + r)) * G3 + cg * 64 + c0] = o;
    }
}

// ================== K2: GRU blocks (3 gate + store wave) | VIT blocks =======
__global__ __launch_bounds__(256, 1)
void gruvit_kernel(const float* __restrict__ xp,
                   const float* __restrict__ Wr,
                   const float* __restrict__ gbias,
                   const int* __restrict__ mask,
                   const float* __restrict__ Dk,
                   const float* __restrict__ db,
                   const float* __restrict__ chain,
                   const float* __restrict__ lb,
                   const float* __restrict__ rb,
                   float* __restrict__ out_pot,
                   float* __restrict__ out_dec,
                   float* __restrict__ out_slen,
                   float* __restrict__ out_chn) {
    __shared__ __align__(16) unsigned char smem[82048];
    const int tid = threadIdx.x;
    const int w = tid >> 6;
    const int l = tid & 63;

    if (blockIdx.x < BB) {
        // =================== GRU block: 4 waves, 1 barrier/step =============
        const int b = blockIdx.x;
        const int bTT = b * TT;
        float (*gbuf)[4 * HH] = (float (*)[4 * HH])(smem);      // 2048 B
        const float* xpg = xp + (size_t)bTT * G3;
        const int j = l;

        if (w < 3) {
            // ---- gate waves (R9-verbatim math; xv direct from global) ----
            float wg[HH];
#pragma unroll
            for (int i2 = 0; i2 < HH; ++i2) wg[i2] = Wr[i2 * G3 + w * HH + j];
#pragma unroll
            for (int i2 = 0; i2 < HH; ++i2) asm volatile("" : "+v"(wg[i2]));
            const float bw = gbias[G3 + w * HH + j];
            __builtin_amdgcn_s_setprio(1);
            float h = 0.f;
            float xv_c = xpg[w * HH + j];                    // xv(0)
            float xv_n = xpg[(size_t)G3 + w * HH + j];       // xv(1)
            int m_c = mask[bTT], m_n = mask[bTT + 1];
            for (int t = 0; t < TT; ++t) {
                float xv_n2 = 0.f; int m_n2 = 0;
                if (t + 2 < TT) {                             // prefetch t+2
                    xv_n2 = xpg[(size_t)(t + 2) * G3 + w * HH + j];
                    m_n2  = mask[bTT + t + 2];
                }
                float a0 = bw, a1 = 0.f, a2 = 0.f, a3 = 0.f;
#pragma unroll
                for (int c = 0; c < HH; c += 4) {
                    a0 += BCAST(h, c + 0) * wg[c + 0];
                    a1 += BCAST(h, c + 1) * wg[c + 1];
                    a2 += BCAST(h, c + 2) * wg[c + 2];
                    a3 += BCAST(h, c + 3) * wg[c + 3];
                }
                float a = (a0 + a1) + (a2 + a3);
                float g = (w == 2) ? a : 1.f / (1.f + __expf(-(xv_c + a)));
                gbuf[t & 1][w * HH + j] = g;
                if (w == 2) gbuf[t & 1][3 * HH + j] = xv_c;
                __syncthreads();
                float z  = gbuf[t & 1][j];
                float r  = gbuf[t & 1][HH + j];
                float rh = gbuf[t & 1][2 * HH + j];
                float xh = gbuf[t & 1][3 * HH + j];
                float y = xh + r * rh;
                float hh = 1.f - 2.f / (1.f + __expf(2.f * y));   // tanh
                float hn = z * h + (1.f - z) * hh;
                h = (m_c != 0) ? hn : h;
                xv_c = xv_n; xv_n = xv_n2; m_c = m_n; m_n = m_n2;
            }
        } else {
            // ---- w3: barrier companion / h-store wave ----
            float h = 0.f;
            int m_c = mask[bTT], m_n = mask[bTT + 1];
            float* hout = (float*)xp + (size_t)bTT * G3;     // h(t) -> xp[t][0:64]
            for (int t = 0; t < TT; ++t) {
                int m_n2 = 0;
                if (t + 2 < TT) m_n2 = mask[bTT + t + 2];
                __syncthreads();
                float z  = gbuf[t & 1][j];
                float r  = gbuf[t & 1][HH + j];
                float rh = gbuf[t & 1][2 * HH + j];
                float xh = gbuf[t & 1][3 * HH + j];
                float y = xh + r * rh;
                float hh = 1.f - 2.f / (1.f + __expf(2.f * y));
                float hn = z * h + (1.f - z) * hh;
                h = (m_c != 0) ? hn : h;
                hout[(size_t)t * G3 + j] = h;                // slot consumed at t-2
                if ((t & 31) == 4) {                         // publish chunk (t>>5)-1
                    const int cp = (t >> 5) - 1;
                    if (cp >= 0 && l == 0) {
                        __threadfence();
                        atomicExch(&g_pflags[b * 32 + cp], 1);
                    }
                }
                m_c = m_n; m_n = m_n2;
            }
            if (l == 0) {                                    // publish chunk 31
                __threadfence();
                atomicExch(&g_pflags[b * 32 + 31], 1);
            }
        }
        return;
    }

    // =================== VIT block: stager(+pot) | viterbi | backtrack ======
    const int b = blockIdx.x - BB;
    const int bTT = b * TT;
    const float* hsrc = xp + (size_t)bTT * G3;               // h at xp[t][0:64]
    float* potg = out_pot + (size_t)bTT * KK;
    const int k = l & 31;
    const int hf = l >> 5;
    const int addrx = (l ^ 32) * 4;

    unsigned char* bp    = smem;                                   // 32736
    unsigned char* table = smem + 32736;                           // 32768
    float (*potbuf)[CH][KK] = (float (*)[CH][KK])(smem + 65504);   // 8192
    float (*hstage)[HH]     = (float (*)[HH])(smem + 73696);       // 8192
    int* ent        = (int*)(smem + 81888);                        // 128
    int* last_tag_s = (int*)(smem + 82016);                        // 4

    float ccol[16];
    int addr[16];
    if (w == 1) {
#pragma unroll
        for (int m = 0; m < 16; ++m) {
            ccol[m] = chain[(hf * 16 + m) * KK + k];
            addr[m] = (hf * 16 + m) * 4;
        }
#pragma unroll
        for (int m = 0; m < 16; ++m) asm volatile("" : "+v"(ccol[m]));
    }
    float dk[HH];
    float dbk = 0.f, lbk = 0.f, rbk = 0.f;
    int sl = 0;
    if (w == 0) {
        // seq length (R9-verbatim) + pot constants
#pragma unroll
        for (int q = 0; q < 16; ++q) sl += mask[bTT + q * 64 + l];
#pragma unroll
        for (int d = 32; d >= 1; d >>= 1) sl += __shfl_xor(sl, d, 64);
        if (l == 0) out_slen[b] = (float)sl;
#pragma unroll
        for (int i2 = 0; i2 < HH; ++i2) dk[i2] = Dk[i2 * KK + k];
#pragma unroll
        for (int i2 = 0; i2 < HH; ++i2) asm volatile("" : "+v"(dk[i2]));
        dbk = db[k]; lbk = lb[k]; rbk = rb[k];
        // ---- stage + pot chunk 0 ----
        if (l == 0) {
            while (atomicAdd(&g_pflags[b * 32 + 0], 0) == 0) __builtin_amdgcn_s_sleep(8);
        }
        __threadfence();                                  // acquire
#pragma unroll
        for (int q = 0; q < 8; ++q) {
            const int idx = q * 64 + l, r = idx >> 4, c4 = idx & 15;
            float4 v = *(const float4*)&hsrc[(size_t)r * G3 + c4 * 4];
            *(float4*)&hstage[r][c4 * 4] = v;
        }
        for (int r = 0; r < 32; ++r) {                    // pot (R9-exact order)
            const float4* hv4 = (const float4*)&hstage[r][0];
            float p0 = dbk, p1 = 0.f, p2 = 0.f, p3 = 0.f;
#pragma unroll
            for (int c = 0; c < 16; ++c) {
                float4 hv = hv4[c];
                p0 += hv.x * dk[4 * c + 0];
                p1 += hv.y * dk[4 * c + 1];
                p2 += hv.z * dk[4 * c + 2];
                p3 += hv.w * dk[4 * c + 3];
            }
            float pot = (p0 + p1) + (p2 + p3);
            if (r == 0) pot += lbk;
            if (r == sl - 1) pot += rbk;
            if (l < 32) {
                potbuf[0][r][k] = pot;
                potg[(size_t)r * KK + k] = pot;
            }
        }
    }
    __syncthreads();                                      // B0: chunk 0 ready
    float s = 0.f;
    for (int c = 0; c < 32; ++c) {
        if (w == 0 && c + 1 < 32) {                       // stage + pot chunk c+1
            const int cc = c + 1;
            if (l == 0) {
                while (atomicAdd(&g_pflags[b * 32 + cc], 0) == 0)
                    __builtin_amdgcn_s_sleep(8);
            }
            __threadfence();
#pragma unroll
            for (int q = 0; q < 8; ++q) {
                const int idx = q * 64 + l, r = idx >> 4, c4 = idx & 15;
                float4 v = *(const float4*)&hsrc[(size_t)(cc * 32 + r) * G3 + c4 * 4];
                *(float4*)&hstage[r][c4 * 4] = v;
            }
            for (int r = 0; r < 32; ++r) {
                const float4* hv4 = (const float4*)&hstage[r][0];
                float p0 = dbk, p1 = 0.f, p2 = 0.f, p3 = 0.f;
#pragma unroll
                for (int cc2 = 0; cc2 < 16; ++cc2) {
                    float4 hv = hv4[cc2];
                    p0 += hv.x * dk[4 * cc2 + 0];
                    p1 += hv.y * dk[4 * cc2 + 1];
                    p2 += hv.z * dk[4 * cc2 + 2];
                    p3 += hv.w * dk[4 * cc2 + 3];
                }
                float pot = (p0 + p1) + (p2 + p3);
                const int t = cc * 32 + r;
                if (t == sl - 1) pot += rbk;
                if (l < 32) {
                    potbuf[cc & 1][r][k] = pot;
                    potg[(size_t)t * KK + k] = pot;
                }
            }
        }
        if (w == 1) {                                     // viterbi chunk c (R9)
            for (int ll = 0; ll < 32; ++ll) {
                const int t = c * 32 + ll;
                float pot = potbuf[c & 1][ll][k];
                if (t == 0) {
                    s = pot;
                } else {
                    const int si = __float_as_int(s);
                    float cc[16];
#pragma unroll
                    for (int m = 0; m < 16; ++m)
                        cc[m] = __int_as_float(__builtin_amdgcn_ds_bpermute(addr[m], si)) + ccol[m];
                    float v1[8]; int i1[8];
#pragma unroll
                    for (int p = 0; p < 8; ++p) {
                        bool tk = cc[2 * p + 1] > cc[2 * p];
                        v1[p] = tk ? cc[2 * p + 1] : cc[2 * p];
                        i1[p] = hf * 16 + (tk ? 2 * p + 1 : 2 * p);
                    }
                    float v2[4]; int i2[4];
#pragma unroll
                    for (int p = 0; p < 4; ++p) {
                        bool tk = v1[2 * p + 1] > v1[2 * p];
                        v2[p] = tk ? v1[2 * p + 1] : v1[2 * p];
                        i2[p] = tk ? i1[2 * p + 1] : i1[2 * p];
                    }
                    float v3[2]; int i3[2];
#pragma unroll
                    for (int p = 0; p < 2; ++p) {
                        bool tk = v2[2 * p + 1] > v2[2 * p];
                        v3[p] = tk ? v2[2 * p + 1] : v2[2 * p];
                        i3[p] = tk ? i2[2 * p + 1] : i2[2 * p];
                    }
                    bool tk = v3[1] > v3[0];
                    float bv = tk ? v3[1] : v3[0];
                    int bi = tk ? i3[1] : i3[0];
                    float ov = __int_as_float(__builtin_amdgcn_ds_bpermute(addrx, __float_as_int(bv)));
                    int   oi = __builtin_amdgcn_ds_bpermute(addrx, bi);
                    bool take = (ov > bv) || (ov == bv && oi < bi);
                    if (take) { bv = ov; bi = oi; }
                    if (l < 32) bp[(t - 1) * KK + k] = (unsigned char)bi;
                    s = bv + pot;
                }
            }
        }
        __syncthreads();                                  // chunk boundary
    }
    if (w == 1) {                                         // last tag (R9)
        float bv = s; int bi = k;
#pragma unroll
        for (int d = 16; d >= 1; d >>= 1) {
            float ov = __shfl_xor(bv, d, 64);
            int   oi = __shfl_xor(bi, d, 64);
            bool take = (ov > bv) || (ov == bv && oi < bi);
            if (take) { bv = ov; bi = oi; }
        }
        if (l == 0) *last_tag_s = bi;
    }
    __syncthreads();
    // ---- Phase A: chunk-parallel backtrack (8 groups over 32 chunks) ----
    {
        const int kk2 = tid & 31;
        const int grp = tid >> 5;                         // 0..7
        for (int c = grp; c < 32; c += 8) {
            int tag = kk2;
            for (int ll = 31; ll >= 0; --ll) {
                const int t = c * 32 + ll;
                if (t < TT - 1) tag = bp[t * KK + tag];
                table[(c * 32 + ll) * KK + kk2] = (unsigned char)tag;
            }
        }
    }
    __syncthreads();
    if (tid == 0) {                                       // Phase B: stitch
        int e = *last_tag_s;
        ent[31] = e;
        for (int c = 30; c >= 0; --c) { e = table[(c + 1) * 32 * KK + e]; ent[c] = e; }
    }
    __syncthreads();
    for (int t = tid; t < TT; t += 256) {                 // Phase C: emit
        const int c = t >> 5, ll = t & 31;
        out_dec[(size_t)bTT + t] = (float)table[(c * 32 + ll) * KK + ent[c]];
    }
    if (blockIdx.x == BB) {
        for (int i2 = tid; i2 < KK * KK; i2 += 256) out_chn[i2] = chain[i2];
    }
    // re-zero this batch's flags for the next launch/replay
    for (int i2 = tid; i2 < 32; i2 += 256) atomicExch(&g_pflags[b * 32 + i2], 0);
}

// ---------------------------------------------------------------------------
extern "C" void kernel_launch(void* const* d_in, const int* in_sizes, int n_in,
                              void* d_out, int out_size, void* d_ws, size_t ws_size,
                              hipStream_t stream) {
    const float* X     = (const float*)d_in[0];
    const int*   mask  = (const int*)d_in[1];
    const float* Wk    = (const float*)d_in[2];   // [128,192]
    const float* Wr    = (const float*)d_in[3];   // [64,192]
    const float* gb    = (const float*)d_in[4];   // [2,192]
    const float* Dk    = (const float*)d_in[5];   // [64,32]
    const float* db    = (const float*)d_in[6];   // [32]
    const float* chain = (const float*)d_in[7];   // [32,32]
    const float* lb    = (const float*)d_in[8];
    const float* rb    = (const float*)d_in[9];

    float* out = (float*)d_out;
    float* out_dec  = out;                                   // [B,T]
    float* out_pot  = out + (size_t)BB * TT;                 // [B,T,K]
    float* out_slen = out + (size_t)BB * TT + (size_t)BB * TT * KK;        // [B]
    float* out_chn  = out_slen + BB;                         // [K,K]

    float* xp = (float*)d_ws;                                // [B*T,192]

    xproj_kernel<<<dim3((BB * TT) / 64, 3), dim3(256), 0, stream>>>(X, Wk, gb, xp);
    gruvit_kernel<<<dim3(2 * BB), dim3(256), 0, stream>>>(xp, Wr, gb, mask, Dk, db,
                                                          chain, lb, rb, out_pot,
                                                          out_dec, out_slen, out_chn);
}